// Round 16
// baseline (1276.060 us; speedup 1.0000x reference)
//
#include <hip/hip_runtime.h>
#include <hip/hip_bf16.h>
#include <stdint.h>

typedef unsigned short u16;
typedef __attribute__((ext_vector_type(8))) short bfrag;   // 8 x bf16 (4 VGPR)
typedef __attribute__((ext_vector_type(4))) float ffrag;   // 4 x f32 accumulator

#define BB 4
#define SS 512
#define DD 1024
#define HH 16
#define HID 4096

__device__ __forceinline__ u16 f2b(float f){
  union { float f; uint32_t u; } v; v.f = f;
  uint32_t r = v.u + 0x7FFFu + ((v.u >> 16) & 1u);   // RNE
  return (u16)(r >> 16);
}

__device__ __forceinline__ void gload_lds16(const void* g, void* l){
  __builtin_amdgcn_global_load_lds(
      (const __attribute__((address_space(1))) uint32_t*)g,
      (__attribute__((address_space(3))) uint32_t*)l, 16, 0, 0);
}

struct GemmArgs {
  const u16*  A[12];
  const u16*  W[12];        // bf16, TRANSPOSED [N][K] (JIT-converted)
  const float* bias[12];
  const float* resid[12];
  float* Cf[12];
  u16*   Cb[12];
  int N, K;
};

// ---------------------------------------------------------------------------
// Batched GEMM — round-13/15 proven body (m97 structure, single-buffered LDS,
// 2 barriers per K-step, both operands via global_load_lds).
// EPI 0: ->bf16 ; 1: relu->bf16 ; 2: +resid ->f32 ; 3: +resid ->f32 & bf16
// ---------------------------------------------------------------------------
template<int EPI, int TN>
__global__ __launch_bounds__(256, 2)
void gemm_kernel(GemmArgs args)
{
  __shared__ u16 As[128*64];     // 16 KB
  __shared__ u16 Bs[TN*64];      // 16 KB (TN=128) / 8 KB (TN=64)

  const int t = threadIdx.x;
  const int N = args.N, K = args.K;
  const int nbn = N / TN;
  const int tiles = 16 * nbn;           // M = 2048 -> 16 bm tiles
  const int cpx = gridDim.x >> 3;       // bijective XCD swizzle (grid % 8 == 0)
  const int wg = (blockIdx.x & 7) * cpx + (blockIdx.x >> 3);
  const int g  = wg / tiles;
  const int rem = wg - g * tiles;
  const int bm = rem / nbn, bn = rem - bm * nbn;

  const u16* Ap = args.A[g] + (size_t)(bm * 128) * K;
  const u16* Wp = args.W[g] + (size_t)(bn * TN) * K;   // [N][K] rows

  const int w = t >> 6, l = t & 63;
  const int wm = w >> 1, wn = w & 1;
  const int lr = l & 15, lg = l >> 4;
  constexpr int NF = TN / 32;           // b-frags per wave

  ffrag acc[4][NF];
  const ffrag zero = {0.f,0.f,0.f,0.f};
  #pragma unroll
  for (int i=0;i<4;i++)
    #pragma unroll
    for (int j=0;j<NF;j++) acc[i][j] = zero;

  auto issueA = [&](int kk){
    #pragma unroll
    for (int i=0;i<4;i++){
      int ch = (w << 6) + l + (i << 8);          // 0..1023, wave-contiguous
      int r = ch >> 3, cl = ch & 7;
      int cs = cl ^ (r & 7);                     // pre-swizzled source chunk
      gload_lds16(Ap + (size_t)r*K + kk + cs*8, As + ch*8);
    }
  };
  auto issueB = [&](int kk){
    constexpr int NCH = (TN * 8) / 256;          // chunks per thread (2 or 4)
    #pragma unroll
    for (int i=0;i<NCH;i++){
      int ch = (w << 6) + l + (i << 8);
      int r = ch >> 3, cl = ch & 7;
      int cs = cl ^ (r & 7);
      gload_lds16(Wp + (size_t)r*K + kk + cs*8, Bs + ch*8);
    }
  };
  auto compute = [&](){
    #pragma unroll
    for (int ks=0; ks<2; ks++){
      bfrag a[4], b[NF];
      const int c = ks*4 + lg;
      #pragma unroll
      for (int fm=0; fm<4; fm++){
        int r = wm*64 + fm*16 + lr;
        a[fm] = *(const bfrag*)((const char*)As + r*128 + ((c ^ (r & 7)) << 4));
      }
      #pragma unroll
      for (int fn=0; fn<NF; fn++){
        int n = wn*(TN/2) + fn*16 + lr;
        b[fn] = *(const bfrag*)((const char*)Bs + n*128 + ((c ^ (n & 7)) << 4));
      }
      #pragma unroll
      for (int fm=0; fm<4; fm++)
        #pragma unroll
        for (int fn=0; fn<NF; fn++)
          acc[fm][fn] = __builtin_amdgcn_mfma_f32_16x16x32_bf16(a[fm], b[fn], acc[fm][fn], 0, 0, 0);
    }
  };

  issueA(0); issueB(0);
  const int nt = K >> 6;
  for (int tt=0; tt<nt; tt++){
    __syncthreads();               // tile tt staged (vmcnt drain)
    compute();
    __syncthreads();               // all waves done reading As/Bs
    if (tt+1 < nt){ issueA((tt+1) << 6); issueB((tt+1) << 6); }
  }

  // epilogue
  const float* biasp = args.bias[g];
  const float* residp = args.resid[g];
  float* Cf = args.Cf[g];
  u16*   Cb = args.Cb[g];
  const int row0 = bm*128 + wm*64;
  const int col0 = bn*TN + wn*(TN/2);
  #pragma unroll
  for (int fn=0; fn<NF; fn++){
    int col = col0 + fn*16 + lr;
    float bv = biasp[col];
    #pragma unroll
    for (int fm=0; fm<4; fm++){
      #pragma unroll
      for (int r=0; r<4; r++){
        int row = row0 + fm*16 + lg*4 + r;
        size_t idx = (size_t)row*N + col;
        float v = acc[fm][fn][r] + bv;
        if (EPI == 1) v = fmaxf(v, 0.f);
        if (EPI >= 2) { v += residp[idx]; Cf[idx] = v; }
        if (EPI == 0 || EPI == 1 || EPI == 3) Cb[idx] = f2b(v);
      }
    }
  }
}

// ---------------------------------------------------------------------------
// Weight convert+transpose: f32 [K][N] -> bf16 [N][K], 64x64 LDS tiles.
// Up to 18 slots (proj + o-proj merged per layer).
// ---------------------------------------------------------------------------
struct WcvtArgs { const float* W[18]; u16* Wt[18]; };

__global__ __launch_bounds__(256)
void wcvt_kernel(WcvtArgs args, int K, int N)
{
  __shared__ float tile[64][65];
  const int nbn = N >> 6;
  const int tilesPerSlot = (K >> 6) * nbn;
  const int slot = blockIdx.x / tilesPerSlot;
  const int rem  = blockIdx.x - slot * tilesPerSlot;
  const int k0 = (rem / nbn) << 6, n0 = (rem - (rem / nbn) * nbn) << 6;
  const float* W = args.W[slot];
  u16* Wt = args.Wt[slot];
  const int t = threadIdx.x;
  #pragma unroll
  for (int i=0;i<4;i++){
    int ch = t + (i<<8);               // 1024 float4 chunks
    int r = ch >> 4, c4 = ch & 15;
    float4 v = *(const float4*)(W + (size_t)(k0+r)*N + n0 + c4*4);
    tile[r][c4*4+0] = v.x; tile[r][c4*4+1] = v.y;
    tile[r][c4*4+2] = v.z; tile[r][c4*4+3] = v.w;
  }
  __syncthreads();
  #pragma unroll
  for (int i=0;i<2;i++){
    int ch = t + (i<<8);               // 512 chunks of 8 bf16
    int nr = ch >> 3, kc = ch & 7;
    u16 tmp[8];
    #pragma unroll
    for (int j=0;j<8;j++) tmp[j] = f2b(tile[kc*8+j][nr]);
    *(uint4*)(Wt + (size_t)(n0+nr)*K + k0 + kc*8) = *(const uint4*)tmp;
  }
}

// ---------------------------------------------------------------------------
// Flash cross-attention (round-15 proven: wave-private Ps, no mid barrier).
// ---------------------------------------------------------------------------
struct FlashArgs {
  const u16* Q[6]; const u16* K[6]; const u16* V[6]; u16* O[6];
};

__global__ __launch_bounds__(256, 3)
void flash_kernel(FlashArgs args)
{
  __shared__ u16 Qs[64*64];   // 8 KB, XOR-swizzled
  __shared__ u16 Ks[64*64];   // 8 KB, XOR-swizzled
  __shared__ u16 Vt[64*64];   // 8 KB, [d][k] transposed, swizzled
  __shared__ u16 Ps[64*64];   // 8 KB, swizzled (wave-private rows)

  const int t = threadIdx.x;
  const int slot = blockIdx.x >> 9;         // /512
  const int rem  = blockIdx.x & 511;
  const int bh = rem >> 3, qt = rem & 7;
  const int b = bh >> 4, h = bh & 15;
  const int s0 = qt * 64;

  const u16* Qg = args.Q[slot];
  const u16* Kg = args.K[slot];
  const u16* Vg = args.V[slot];
  u16* Og = args.O[slot];

  const int w = t >> 6, l = t & 63;
  const int lr = l & 15, lg = l >> 4;
  const float SCALE = 0.125f;

  // stage Q tile once: 512 chunks of 16B -> 2 per thread
  #pragma unroll
  for (int i=0;i<2;i++){
    int ch = (w << 6) + l + (i << 8);
    int r = ch >> 3, cl = ch & 7;
    int cs = cl ^ (r & 7);
    gload_lds16(Qg + ((size_t)(b*SS + s0 + r))*DD + h*64 + cs*8, Qs + ch*8);
  }

  float mprev[4], lsum[4];
  #pragma unroll
  for (int r=0;r<4;r++){ mprev[r] = -INFINITY; lsum[r] = 0.f; }
  ffrag oacc[4];
  const ffrag zero = {0.f,0.f,0.f,0.f};
  #pragma unroll
  for (int i=0;i<4;i++) oacc[i] = zero;

  // V transpose staging geometry
  const int kb = t >> 4, nb = t & 15;
  const int k0 = kb*4, n0 = nb*4;

  for (int kt=0; kt<8; kt++){
    const int ks0 = kt*64;
    // ---- stage K (async gload) ----
    #pragma unroll
    for (int i=0;i<2;i++){
      int ch = (w << 6) + l + (i << 8);
      int r = ch >> 3, cl = ch & 7;
      int cs = cl ^ (r & 7);
      gload_lds16(Kg + ((size_t)(b*SS + ks0 + r))*DD + h*64 + cs*8, Ks + ch*8);
    }
    // ---- stage V transposed [d][k] ----
    {
      u16 va[4][4];
      #pragma unroll
      for (int i=0;i<4;i++)
        *(uint2*)va[i] = *(const uint2*)(Vg + ((size_t)(b*SS + ks0 + k0 + i))*DD + h*64 + n0);
      #pragma unroll
      for (int j=0;j<4;j++){
        int n = n0 + j;
        ushort4 pk;
        pk.x = va[0][j]; pk.y = va[1][j]; pk.z = va[2][j]; pk.w = va[3][j];
        *(ushort4*)((char*)Vt + n*128 + (((k0>>3) ^ (n&7))<<4) + ((k0&7)<<1)) = pk;
      }
    }
    __syncthreads();

    // ---- S = Q K^T (per wave: 16 q-rows x 64 k) ----
    ffrag sacc[4];
    #pragma unroll
    for (int i=0;i<4;i++) sacc[i] = zero;
    #pragma unroll
    for (int ks=0; ks<2; ks++){
      const int c = ks*4 + lg;
      int rq = w*16 + lr;
      bfrag a = *(const bfrag*)((const char*)Qs + rq*128 + ((c ^ (rq&7))<<4));
      #pragma unroll
      for (int fn=0; fn<4; fn++){
        int rk = fn*16 + lr;
        bfrag bb = *(const bfrag*)((const char*)Ks + rk*128 + ((c ^ (rk&7))<<4));
        sacc[fn] = __builtin_amdgcn_mfma_f32_16x16x32_bf16(a, bb, sacc[fn], 0, 0, 0);
      }
    }

    // ---- online softmax (rows = w*16 + lg*4 + rr; cols = fn*16 + lr) ----
    #pragma unroll
    for (int rr=0; rr<4; rr++){
      float s0v = sacc[0][rr]*SCALE, s1v = sacc[1][rr]*SCALE;
      float s2v = sacc[2][rr]*SCALE, s3v = sacc[3][rr]*SCALE;
      float mx = fmaxf(fmaxf(s0v,s1v), fmaxf(s2v,s3v));
      #pragma unroll
      for (int o=1;o<16;o<<=1) mx = fmaxf(mx, __shfl_xor(mx, o));
      float nm = fmaxf(mprev[rr], mx);
      float fac = __expf(mprev[rr] - nm);
      mprev[rr] = nm;
      float p0 = __expf(s0v - nm), p1 = __expf(s1v - nm);
      float p2 = __expf(s2v - nm), p3 = __expf(s3v - nm);
      float psum = (p0+p1)+(p2+p3);
      #pragma unroll
      for (int o=1;o<16;o<<=1) psum += __shfl_xor(psum, o);
      lsum[rr] = lsum[rr]*fac + psum;
      #pragma unroll
      for (int fn=0; fn<4; fn++) oacc[fn][rr] *= fac;
      // write P to LDS (bf16, swizzled); Ps rows are wave-private
      int row = w*16 + lg*4 + rr;
      int swz = (row & 7) << 4;
      float pv[4] = {p0,p1,p2,p3};
      #pragma unroll
      for (int fn=0; fn<4; fn++){
        int col = fn*16 + lr;
        int addr = row*128 + ((((col>>3)<<4) ^ swz)) + ((col&7)<<1);
        *(u16*)((char*)Ps + addr) = f2b(pv[fn]);
      }
    }
    __builtin_amdgcn_sched_barrier(0);   // pin P-writes before PV reads

    // ---- O += P V (no block barrier: each wave reads only its own Ps rows) ----
    #pragma unroll
    for (int ks=0; ks<2; ks++){
      const int c = ks*4 + lg;
      int rq = w*16 + lr;
      bfrag a = *(const bfrag*)((const char*)Ps + rq*128 + ((c ^ (rq&7))<<4));
      #pragma unroll
      for (int fn=0; fn<4; fn++){
        int n = fn*16 + lr;
        bfrag bb = *(const bfrag*)((const char*)Vt + n*128 + ((c ^ (n&7))<<4));
        oacc[fn] = __builtin_amdgcn_mfma_f32_16x16x32_bf16(a, bb, oacc[fn], 0, 0, 0);
      }
    }
    __syncthreads();   // safe to restage Ks/Vt/Ps
  }

  // ---- epilogue: O / l ----
  float inv[4];
  #pragma unroll
  for (int rr=0; rr<4; rr++) inv[rr] = 1.f / lsum[rr];
  #pragma unroll
  for (int fn=0; fn<4; fn++){
    int col = h*64 + fn*16 + lr;
    #pragma unroll
    for (int rr=0; rr<4; rr++){
      int qrow = s0 + w*16 + lg*4 + rr;
      Og[((size_t)(b*SS + qrow))*DD + col] = f2b(oacc[fn][rr] * inv[rr]);
    }
  }
}

// ---------------------------------------------------------------------------
// LayerNorm, 6-slot batched: grid 12288 (6 tensors x 2048 rows), D=1024.
// ---------------------------------------------------------------------------
struct LnArgs {
  const float* X[6]; const float* g[6]; const float* b[6]; u16* O[6];
};

__device__ __forceinline__ float block_reduce_sum(float v){
  #pragma unroll
  for (int o=32;o;o>>=1) v += __shfl_xor(v,o);
  __shared__ float sm[4];
  if ((threadIdx.x&63)==0) sm[threadIdx.x>>6] = v;
  __syncthreads();
  float r = sm[0]+sm[1]+sm[2]+sm[3];
  __syncthreads();
  return r;
}

__global__ __launch_bounds__(256)
void ln6_kernel(LnArgs args)
{
  const int bi = blockIdx.x >> 11;
  const int row = blockIdx.x & 2047;
  const float* x = args.X[bi] + (size_t)row*DD;
  const int t = threadIdx.x;
  float4 v = ((const float4*)x)[t];
  float mean = block_reduce_sum(v.x+v.y+v.z+v.w) * (1.f/DD);
  float d0=v.x-mean, d1=v.y-mean, d2=v.z-mean, d3=v.w-mean;
  float var = block_reduce_sum(d0*d0+d1*d1+d2*d2+d3*d3) * (1.f/DD);
  float rs = rsqrtf(var + 1e-5f);
  float4 gg = ((const float4*)args.g[bi])[t];
  float4 bb = ((const float4*)args.b[bi])[t];
  ushort4 o;
  o.x = f2b(d0*rs*gg.x + bb.x);
  o.y = f2b(d1*rs*gg.y + bb.y);
  o.z = f2b(d2*rs*gg.z + bb.z);
  o.w = f2b(d3*rs*gg.w + bb.w);
  ((ushort4*)(args.O[bi] + (size_t)row*DD))[t] = o;
}

__global__ __launch_bounds__(256)
void cvt_kernel(const float* __restrict__ in, u16* __restrict__ out)
{
  size_t i = ((size_t)blockIdx.x*256 + threadIdx.x)*8;
  float4 a = *(const float4*)(in+i);
  float4 b = *(const float4*)(in+i+4);
  ushort4 o0, o1;
  o0.x=f2b(a.x); o0.y=f2b(a.y); o0.z=f2b(a.z); o0.w=f2b(a.w);
  o1.x=f2b(b.x); o1.y=f2b(b.y); o1.z=f2b(b.z); o1.w=f2b(b.w);
  *(ushort4*)(out+i) = o0;
  *(ushort4*)(out+i+4) = o1;
}

// ---------------------------------------------------------------------------
extern "C" void kernel_launch(void* const* d_in, const int* in_sizes, int n_in,
                              void* d_out, int out_size, void* d_ws, size_t ws_size,
                              hipStream_t stream)
{
  (void)in_sizes; (void)n_in; (void)out_size; (void)ws_size;
  const float* text   = (const float*)d_in[0];
  const float* audio  = (const float*)d_in[1];
  const float* visual = (const float*)d_in[2];
  const float* WQ  = (const float*)d_in[3];
  const float* bQ  = (const float*)d_in[4];
  const float* WK  = (const float*)d_in[5];
  const float* bK  = (const float*)d_in[6];
  const float* WV1 = (const float*)d_in[7];
  const float* bV1 = (const float*)d_in[8];
  const float* WV2 = (const float*)d_in[9];
  const float* bV2 = (const float*)d_in[10];
  const float* WO1 = (const float*)d_in[11];
  const float* bO1 = (const float*)d_in[12];
  const float* WO2 = (const float*)d_in[13];
  const float* bO2 = (const float*)d_in[14];
  const float* F1W1 = (const float*)d_in[15];
  const float* F1b1 = (const float*)d_in[16];
  const float* F1W2 = (const float*)d_in[17];
  const float* F1b2 = (const float*)d_in[18];
  const float* F2W1 = (const float*)d_in[19];
  const float* F2b1 = (const float*)d_in[20];
  const float* F2W2 = (const float*)d_in[21];
  const float* F2b2 = (const float*)d_in[22];
  const float* LN1g = (const float*)d_in[23];
  const float* LN1b = (const float*)d_in[24];
  const float* LN2g = (const float*)d_in[25];
  const float* LN2b = (const float*)d_in[26];
  float* outp = (float*)d_out;

  // ws layout: round-15 proven 260 MB (212 + 48 JIT weight buffer).
  char* ws = (char*)d_ws;
  size_t off = 0;
  auto alloc = [&](size_t bytes)->char*{
    char* p = ws + off; off += (bytes + 255) & ~(size_t)255; return p;
  };
  const size_t NTOK = (size_t)BB*SS;          // 2048 rows
  const size_t AB = NTOK*DD*2;                // bf16 activation bytes (4MB)
  const size_t E  = NTOK*DD;                  // activation elements (2M)

  u16* inb[3];
  for (int i=0;i<3;i++) inb[i] = (u16*)alloc(AB);
  u16 *Qb[3], *Kb[3], *V1b[3], *V2b[3], *nV1b[3], *nV2b[3];
  for (int i=0;i<3;i++){
    Qb[i]=(u16*)alloc(AB); Kb[i]=(u16*)alloc(AB);
    V1b[i]=(u16*)alloc(AB); V2b[i]=(u16*)alloc(AB);
  }
  for (int i=0;i<3;i++){ nV1b[i]=(u16*)alloc(AB); nV2b[i]=(u16*)alloc(AB); }
  float* Lgp = (float*)alloc((size_t)BB*HH*SS*SS*4);   // 64MB (h-alias region)
  u16* P1p   = (u16*)alloc((size_t)BB*HH*SS*SS*2);     // 32MB (h-alias region)
  u16* P2Tp  = (u16*)alloc((size_t)BB*HH*SS*SS*2);     // 32MB (mid-alias region)
  u16* Wtb   = (u16*)alloc((size_t)6*DD*HID*2);        // 48MB JIT weight buffer

  // aliases (dead-phase reuse). h buffers are 4E elements each.
  u16 *x1b[3], *x2b[3], *h1b[3], *h2b[3], *mid1b[3], *mid2b[3];
  for (int i=0;i<3;i++){ x1b[i]=Qb[i]; x2b[i]=Kb[i]; }
  u16* Lgu = (u16*)Lgp;
  h1b[0]=Lgu;        h2b[0]=Lgu+ 4*E;   // Lg = 16E: four 4E h-buffers
  h1b[1]=Lgu+8*E;    h2b[1]=Lgu+12*E;
  h1b[2]=P1p;        h2b[2]=P1p+ 4*E;   // P1 = 16E: two 4E h-buffers
  for (int i=0;i<3;i++){ mid1b[i]=P2Tp+(size_t)(2*i)*E; mid2b[i]=P2Tp+(size_t)(2*i+1)*E; }

  cvt_kernel<<<1024,256,0,stream>>>(text, inb[0]);
  cvt_kernel<<<1024,256,0,stream>>>(audio, inb[1]);
  cvt_kernel<<<1024,256,0,stream>>>(visual, inb[2]);

  const size_t OSZ = E;
  const size_t DD2 = (size_t)DD*DD;
  const size_t DH = (size_t)DD*HID;
  struct Br { const float* f1; const u16* b1; const float* f2; const u16* b2; int s1, s2; };
  Br brs[3] = {{text,inb[0],audio,inb[1],0,1},{text,inb[0],visual,inb[2],2,3},{audio,inb[1],visual,inb[2],4,5}};

  for (int li=0; li<2; li++){
    const u16* m1b[3]; const u16* m2b[3];
    float* t1f[3]; float* t2f[3];
    for (int bi=0; bi<3; bi++){
      m1b[bi] = li==0 ? brs[bi].b1 : mid1b[bi];
      m2b[bi] = li==0 ? brs[bi].b2 : mid2b[bi];
      t1f[bi] = outp + (size_t)brs[bi].s1*OSZ;   // residual stream lives in d_out
      t2f[bi] = outp + (size_t)brs[bi].s2*OSZ;
    }

    // ---- merged wcvt: proj (slots 0-11) + o-proj (slots 12-17), grid 4608 ----
    {
      WcvtArgs wa{};
      for (int bi=0; bi<3; bi++){
        const int i = bi*2 + li;
        wa.W[bi*4+0]=WQ +i*DD2; wa.W[bi*4+1]=WK +i*DD2;
        wa.W[bi*4+2]=WV1+i*DD2; wa.W[bi*4+3]=WV2+i*DD2;
        for (int s=0;s<4;s++) wa.Wt[bi*4+s] = Wtb + (size_t)(bi*4+s)*DD2;
        wa.W[12+bi*2+0]=WO1+i*DD2; wa.W[12+bi*2+1]=WO2+i*DD2;
        wa.Wt[12+bi*2+0]=Wtb + (size_t)(12+bi*2+0)*DD2;
        wa.Wt[12+bi*2+1]=Wtb + (size_t)(12+bi*2+1)*DD2;
      }
      wcvt_kernel<<<4608,256,0,stream>>>(wa, DD, DD);
    }
    // ---- projections: 12-slot GEMM (TN=128, grid 1536) ----
    {
      GemmArgs ga{};
      for (int bi=0; bi<3; bi++){
        const int i = bi*2 + li;
        ga.A[bi*4+0]=m1b[bi]; ga.bias[bi*4+0]=bQ +(size_t)i*DD; ga.Cb[bi*4+0]=Qb[bi];
        ga.A[bi*4+1]=m2b[bi]; ga.bias[bi*4+1]=bK +(size_t)i*DD; ga.Cb[bi*4+1]=Kb[bi];
        ga.A[bi*4+2]=m1b[bi]; ga.bias[bi*4+2]=bV1+(size_t)i*DD; ga.Cb[bi*4+2]=V1b[bi];
        ga.A[bi*4+3]=m2b[bi]; ga.bias[bi*4+3]=bV2+(size_t)i*DD; ga.Cb[bi*4+3]=V2b[bi];
        for (int s=0;s<4;s++) ga.W[bi*4+s] = Wtb + (size_t)(bi*4+s)*DD2;
      }
      ga.N = DD; ga.K = DD;
      gemm_kernel<0,128><<<1536,256,0,stream>>>(ga);
    }
    // ---- flash attention: 6 slots (3 branches x 2 dirs), grid 3072 ----
    {
      FlashArgs fa{};
      for (int bi=0; bi<3; bi++){
        fa.Q[bi*2+0]=Qb[bi]; fa.K[bi*2+0]=Kb[bi]; fa.V[bi*2+0]=V2b[bi]; fa.O[bi*2+0]=nV2b[bi];
        fa.Q[bi*2+1]=Kb[bi]; fa.K[bi*2+1]=Qb[bi]; fa.V[bi*2+1]=V1b[bi]; fa.O[bi*2+1]=nV1b[bi];
      }
      flash_kernel<<<3072,256,0,stream>>>(fa);
    }
    // ---- output projections: 6-slot GEMM (TN=128, grid 768; Wtb slots 12-17) ----
    {
      GemmArgs ga{};
      for (int bi=0; bi<3; bi++){
        const int i = bi*2 + li;
        ga.A[bi*2+0]=nV1b[bi]; ga.bias[bi*2+0]=bO1+(size_t)i*DD;
        ga.resid[bi*2+0] = li==0 ? brs[bi].f1 : t1f[bi]; ga.Cf[bi*2+0]=t1f[bi];
        ga.A[bi*2+1]=nV2b[bi]; ga.bias[bi*2+1]=bO2+(size_t)i*DD;
        ga.resid[bi*2+1] = li==0 ? brs[bi].f2 : t2f[bi]; ga.Cf[bi*2+1]=t2f[bi];
        ga.W[bi*2+0]=Wtb + (size_t)(12+bi*2+0)*DD2;
        ga.W[bi*2+1]=Wtb + (size_t)(12+bi*2+1)*DD2;
      }
      ga.N = DD; ga.K = DD;
      gemm_kernel<2,128><<<768,256,0,stream>>>(ga);
    }
    // ---- LN: single 6-slot dispatch, grid 12288 ----
    {
      LnArgs la{};
      for (int bi=0; bi<3; bi++){
        const int i = bi*2 + li;
        la.X[bi*2+0]=t1f[bi]; la.g[bi*2+0]=LN1g+(size_t)i*DD; la.b[bi*2+0]=LN1b+(size_t)i*DD; la.O[bi*2+0]=x1b[bi];
        la.X[bi*2+1]=t2f[bi]; la.g[bi*2+1]=LN2g+(size_t)i*DD; la.b[bi*2+1]=LN2b+(size_t)i*DD; la.O[bi*2+1]=x2b[bi];
      }
      ln6_kernel<<<12288,256,0,stream>>>(la);
    }
    // ---- FFN up: JIT-convert, then 6-slot GEMM (N=4096, TN=128, grid 3072) ----
    {
      WcvtArgs wa{};
      for (int bi=0; bi<3; bi++){
        const int i = bi*2 + li;
        wa.W[bi*2+0]=F1W1+(size_t)i*DH; wa.W[bi*2+1]=F2W1+(size_t)i*DH;
        wa.Wt[bi*2+0]=Wtb + (size_t)(bi*2+0)*DH;
        wa.Wt[bi*2+1]=Wtb + (size_t)(bi*2+1)*DH;
      }
      wcvt_kernel<<<6144,256,0,stream>>>(wa, DD, HID);
      GemmArgs ga{};
      for (int bi=0; bi<3; bi++){
        const int i = bi*2 + li;
        ga.A[bi*2+0]=x1b[bi]; ga.bias[bi*2+0]=F1b1+(size_t)i*HID; ga.Cb[bi*2+0]=h1b[bi];
        ga.A[bi*2+1]=x2b[bi]; ga.bias[bi*2+1]=F2b1+(size_t)i*HID; ga.Cb[bi*2+1]=h2b[bi];
        ga.W[bi*2+0]=Wtb + (size_t)(bi*2+0)*DH;
        ga.W[bi*2+1]=Wtb + (size_t)(bi*2+1)*DH;
      }
      ga.N = HID; ga.K = DD;
      gemm_kernel<1,128><<<3072,256,0,stream>>>(ga);
    }
    // ---- FFN down: JIT-convert, then 6-slot GEMM (K=4096, TN=64, grid 1536) ----
    {
      WcvtArgs wa{};
      for (int bi=0; bi<3; bi++){
        const int i = bi*2 + li;
        wa.W[bi*2+0]=F1W2+(size_t)i*DH; wa.W[bi*2+1]=F2W2+(size_t)i*DH;
        wa.Wt[bi*2+0]=Wtb + (size_t)(bi*2+0)*DH;
        wa.Wt[bi*2+1]=Wtb + (size_t)(bi*2+1)*DH;
      }
      wcvt_kernel<<<6144,256,0,stream>>>(wa, HID, DD);
      GemmArgs ga{};
      for (int bi=0; bi<3; bi++){
        const int i = bi*2 + li;
        ga.A[bi*2+0]=h1b[bi]; ga.bias[bi*2+0]=F1b2+(size_t)i*DD;
        ga.resid[bi*2+0]=t1f[bi]; ga.Cf[bi*2+0]=t1f[bi]; ga.Cb[bi*2+0]=mid1b[bi];
        ga.A[bi*2+1]=h2b[bi]; ga.bias[bi*2+1]=F2b2+(size_t)i*DD;
        ga.resid[bi*2+1]=t2f[bi]; ga.Cf[bi*2+1]=t2f[bi]; ga.Cb[bi*2+1]=mid2b[bi];
        ga.W[bi*2+0]=Wtb + (size_t)(bi*2+0)*DH;
        ga.W[bi*2+1]=Wtb + (size_t)(bi*2+1)*DH;
      }
      ga.N = DD; ga.K = HID;
      if (li == 0) gemm_kernel<3,64><<<1536,256,0,stream>>>(ga);
      else         gemm_kernel<2,64><<<1536,256,0,stream>>>(ga);
    }
  }
}

// Round 17
// 1230.084 us; speedup vs baseline: 1.0374x; 1.0374x over previous
//
#include <hip/hip_runtime.h>
#include <hip/hip_bf16.h>
#include <stdint.h>

typedef unsigned short u16;
typedef __attribute__((ext_vector_type(8))) short bfrag;   // 8 x bf16 (4 VGPR)
typedef __attribute__((ext_vector_type(4))) float ffrag;   // 4 x f32 accumulator

#define BB 4
#define SS 512
#define DD 1024
#define HH 16
#define HID 4096

__device__ __forceinline__ u16 f2b(float f){
  union { float f; uint32_t u; } v; v.f = f;
  uint32_t r = v.u + 0x7FFFu + ((v.u >> 16) & 1u);   // RNE
  return (u16)(r >> 16);
}

__device__ __forceinline__ void gload_lds16(const void* g, void* l){
  __builtin_amdgcn_global_load_lds(
      (const __attribute__((address_space(1))) uint32_t*)g,
      (__attribute__((address_space(3))) uint32_t*)l, 16, 0, 0);
}

struct GemmArgs {
  const u16*  A[12];
  const u16*  W[12];        // bf16, TRANSPOSED [N][K] (JIT-converted)
  const float* bias[12];
  const float* resid[12];
  float* Cf[12];
  u16*   Cb[12];
  int N, K;
};

// ---------------------------------------------------------------------------
// Batched GEMM — round-15 proven body (m97 structure, single-buffered LDS,
// 2 barriers per K-step, both operands via global_load_lds).
// EPI 0: ->bf16 ; 1: relu->bf16 ; 2: +resid ->f32 ; 3: +resid ->f32 & bf16
// ---------------------------------------------------------------------------
template<int EPI, int TN>
__global__ __launch_bounds__(256, 2)
void gemm_kernel(GemmArgs args)
{
  __shared__ u16 As[128*64];     // 16 KB
  __shared__ u16 Bs[TN*64];      // 16 KB (TN=128)

  const int t = threadIdx.x;
  const int N = args.N, K = args.K;
  const int nbn = N / TN;
  const int tiles = 16 * nbn;           // M = 2048 -> 16 bm tiles
  const int cpx = gridDim.x >> 3;       // bijective XCD swizzle (grid % 8 == 0)
  const int wg = (blockIdx.x & 7) * cpx + (blockIdx.x >> 3);
  const int g  = wg / tiles;
  const int rem = wg - g * tiles;
  const int bm = rem / nbn, bn = rem - bm * nbn;

  const u16* Ap = args.A[g] + (size_t)(bm * 128) * K;
  const u16* Wp = args.W[g] + (size_t)(bn * TN) * K;   // [N][K] rows

  const int w = t >> 6, l = t & 63;
  const int wm = w >> 1, wn = w & 1;
  const int lr = l & 15, lg = l >> 4;
  constexpr int NF = TN / 32;           // b-frags per wave

  ffrag acc[4][NF];
  const ffrag zero = {0.f,0.f,0.f,0.f};
  #pragma unroll
  for (int i=0;i<4;i++)
    #pragma unroll
    for (int j=0;j<NF;j++) acc[i][j] = zero;

  auto issueA = [&](int kk){
    #pragma unroll
    for (int i=0;i<4;i++){
      int ch = (w << 6) + l + (i << 8);          // 0..1023, wave-contiguous
      int r = ch >> 3, cl = ch & 7;
      int cs = cl ^ (r & 7);                     // pre-swizzled source chunk
      gload_lds16(Ap + (size_t)r*K + kk + cs*8, As + ch*8);
    }
  };
  auto issueB = [&](int kk){
    constexpr int NCH = (TN * 8) / 256;          // chunks per thread (2 or 4)
    #pragma unroll
    for (int i=0;i<NCH;i++){
      int ch = (w << 6) + l + (i << 8);
      int r = ch >> 3, cl = ch & 7;
      int cs = cl ^ (r & 7);
      gload_lds16(Wp + (size_t)r*K + kk + cs*8, Bs + ch*8);
    }
  };
  auto compute = [&](){
    #pragma unroll
    for (int ks=0; ks<2; ks++){
      bfrag a[4], b[NF];
      const int c = ks*4 + lg;
      #pragma unroll
      for (int fm=0; fm<4; fm++){
        int r = wm*64 + fm*16 + lr;
        a[fm] = *(const bfrag*)((const char*)As + r*128 + ((c ^ (r & 7)) << 4));
      }
      #pragma unroll
      for (int fn=0; fn<NF; fn++){
        int n = wn*(TN/2) + fn*16 + lr;
        b[fn] = *(const bfrag*)((const char*)Bs + n*128 + ((c ^ (n & 7)) << 4));
      }
      #pragma unroll
      for (int fm=0; fm<4; fm++)
        #pragma unroll
        for (int fn=0; fn<NF; fn++)
          acc[fm][fn] = __builtin_amdgcn_mfma_f32_16x16x32_bf16(a[fm], b[fn], acc[fm][fn], 0, 0, 0);
    }
  };

  issueA(0); issueB(0);
  const int nt = K >> 6;
  for (int tt=0; tt<nt; tt++){
    __syncthreads();               // tile tt staged (vmcnt drain)
    compute();
    __syncthreads();               // all waves done reading As/Bs
    if (tt+1 < nt){ issueA((tt+1) << 6); issueB((tt+1) << 6); }
  }

  // epilogue
  const float* biasp = args.bias[g];
  const float* residp = args.resid[g];
  float* Cf = args.Cf[g];
  u16*   Cb = args.Cb[g];
  const int row0 = bm*128 + wm*64;
  const int col0 = bn*TN + wn*(TN/2);
  #pragma unroll
  for (int fn=0; fn<NF; fn++){
    int col = col0 + fn*16 + lr;
    float bv = biasp[col];
    #pragma unroll
    for (int fm=0; fm<4; fm++){
      #pragma unroll
      for (int r=0; r<4; r++){
        int row = row0 + fm*16 + lg*4 + r;
        size_t idx = (size_t)row*N + col;
        float v = acc[fm][fn][r] + bv;
        if (EPI == 1) v = fmaxf(v, 0.f);
        if (EPI >= 2) { v += residp[idx]; Cf[idx] = v; }
        if (EPI == 0 || EPI == 1 || EPI == 3) Cb[idx] = f2b(v);
      }
    }
  }
}

// ---------------------------------------------------------------------------
// Weight convert+transpose: f32 [K][N] -> bf16 [N][K], 64x64 LDS tiles.
// Up to 18 slots (proj + o-proj merged per layer).
// ---------------------------------------------------------------------------
struct WcvtArgs { const float* W[18]; u16* Wt[18]; };

__global__ __launch_bounds__(256)
void wcvt_kernel(WcvtArgs args, int K, int N)
{
  __shared__ float tile[64][65];
  const int nbn = N >> 6;
  const int tilesPerSlot = (K >> 6) * nbn;
  const int slot = blockIdx.x / tilesPerSlot;
  const int rem  = blockIdx.x - slot * tilesPerSlot;
  const int k0 = (rem / nbn) << 6, n0 = (rem - (rem / nbn) * nbn) << 6;
  const float* W = args.W[slot];
  u16* Wt = args.Wt[slot];
  const int t = threadIdx.x;
  #pragma unroll
  for (int i=0;i<4;i++){
    int ch = t + (i<<8);               // 1024 float4 chunks
    int r = ch >> 4, c4 = ch & 15;
    float4 v = *(const float4*)(W + (size_t)(k0+r)*N + n0 + c4*4);
    tile[r][c4*4+0] = v.x; tile[r][c4*4+1] = v.y;
    tile[r][c4*4+2] = v.z; tile[r][c4*4+3] = v.w;
  }
  __syncthreads();
  #pragma unroll
  for (int i=0;i<2;i++){
    int ch = t + (i<<8);               // 512 chunks of 8 bf16
    int nr = ch >> 3, kc = ch & 7;
    u16 tmp[8];
    #pragma unroll
    for (int j=0;j<8;j++) tmp[j] = f2b(tile[kc*8+j][nr]);
    *(uint4*)(Wt + (size_t)(n0+nr)*K + k0 + kc*8) = *(const uint4*)tmp;
  }
}

// ---------------------------------------------------------------------------
// Flash cross-attention (round-15 proven body) + T1 XCD swizzle: the 8
// q-tile blocks of each (slot,bh) share a 256KB K/V panel; mapping them to
// one XCD's L2 (bijective swizzle, grid 3072 % 8 == 0) captures the reuse.
// ---------------------------------------------------------------------------
struct FlashArgs {
  const u16* Q[6]; const u16* K[6]; const u16* V[6]; u16* O[6];
};

__global__ __launch_bounds__(256, 3)
void flash_kernel(FlashArgs args)
{
  __shared__ u16 Qs[64*64];   // 8 KB, XOR-swizzled
  __shared__ u16 Ks[64*64];   // 8 KB, XOR-swizzled
  __shared__ u16 Vt[64*64];   // 8 KB, [d][k] transposed, swizzled
  __shared__ u16 Ps[64*64];   // 8 KB, swizzled (wave-private rows)

  const int t = threadIdx.x;
  const int cpx = gridDim.x >> 3;           // XCD swizzle
  const int wgid = (blockIdx.x & 7) * cpx + (blockIdx.x >> 3);
  const int slot = wgid >> 9;               // /512
  const int rem  = wgid & 511;
  const int bh = rem >> 3, qt = rem & 7;
  const int b = bh >> 4, h = bh & 15;
  const int s0 = qt * 64;

  const u16* Qg = args.Q[slot];
  const u16* Kg = args.K[slot];
  const u16* Vg = args.V[slot];
  u16* Og = args.O[slot];

  const int w = t >> 6, l = t & 63;
  const int lr = l & 15, lg = l >> 4;
  const float SCALE = 0.125f;

  // stage Q tile once: 512 chunks of 16B -> 2 per thread
  #pragma unroll
  for (int i=0;i<2;i++){
    int ch = (w << 6) + l + (i << 8);
    int r = ch >> 3, cl = ch & 7;
    int cs = cl ^ (r & 7);
    gload_lds16(Qg + ((size_t)(b*SS + s0 + r))*DD + h*64 + cs*8, Qs + ch*8);
  }

  float mprev[4], lsum[4];
  #pragma unroll
  for (int r=0;r<4;r++){ mprev[r] = -INFINITY; lsum[r] = 0.f; }
  ffrag oacc[4];
  const ffrag zero = {0.f,0.f,0.f,0.f};
  #pragma unroll
  for (int i=0;i<4;i++) oacc[i] = zero;

  // V transpose staging geometry
  const int kb = t >> 4, nb = t & 15;
  const int k0 = kb*4, n0 = nb*4;

  for (int kt=0; kt<8; kt++){
    const int ks0 = kt*64;
    // ---- stage K (async gload) ----
    #pragma unroll
    for (int i=0;i<2;i++){
      int ch = (w << 6) + l + (i << 8);
      int r = ch >> 3, cl = ch & 7;
      int cs = cl ^ (r & 7);
      gload_lds16(Kg + ((size_t)(b*SS + ks0 + r))*DD + h*64 + cs*8, Ks + ch*8);
    }
    // ---- stage V transposed [d][k] ----
    {
      u16 va[4][4];
      #pragma unroll
      for (int i=0;i<4;i++)
        *(uint2*)va[i] = *(const uint2*)(Vg + ((size_t)(b*SS + ks0 + k0 + i))*DD + h*64 + n0);
      #pragma unroll
      for (int j=0;j<4;j++){
        int n = n0 + j;
        ushort4 pk;
        pk.x = va[0][j]; pk.y = va[1][j]; pk.z = va[2][j]; pk.w = va[3][j];
        *(ushort4*)((char*)Vt + n*128 + (((k0>>3) ^ (n&7))<<4) + ((k0&7)<<1)) = pk;
      }
    }
    __syncthreads();

    // ---- S = Q K^T (per wave: 16 q-rows x 64 k) ----
    ffrag sacc[4];
    #pragma unroll
    for (int i=0;i<4;i++) sacc[i] = zero;
    #pragma unroll
    for (int ks=0; ks<2; ks++){
      const int c = ks*4 + lg;
      int rq = w*16 + lr;
      bfrag a = *(const bfrag*)((const char*)Qs + rq*128 + ((c ^ (rq&7))<<4));
      #pragma unroll
      for (int fn=0; fn<4; fn++){
        int rk = fn*16 + lr;
        bfrag bb = *(const bfrag*)((const char*)Ks + rk*128 + ((c ^ (rk&7))<<4));
        sacc[fn] = __builtin_amdgcn_mfma_f32_16x16x32_bf16(a, bb, sacc[fn], 0, 0, 0);
      }
    }

    // ---- online softmax (rows = w*16 + lg*4 + rr; cols = fn*16 + lr) ----
    #pragma unroll
    for (int rr=0; rr<4; rr++){
      float s0v = sacc[0][rr]*SCALE, s1v = sacc[1][rr]*SCALE;
      float s2v = sacc[2][rr]*SCALE, s3v = sacc[3][rr]*SCALE;
      float mx = fmaxf(fmaxf(s0v,s1v), fmaxf(s2v,s3v));
      #pragma unroll
      for (int o=1;o<16;o<<=1) mx = fmaxf(mx, __shfl_xor(mx, o));
      float nm = fmaxf(mprev[rr], mx);
      float fac = __expf(mprev[rr] - nm);
      mprev[rr] = nm;
      float p0 = __expf(s0v - nm), p1 = __expf(s1v - nm);
      float p2 = __expf(s2v - nm), p3 = __expf(s3v - nm);
      float psum = (p0+p1)+(p2+p3);
      #pragma unroll
      for (int o=1;o<16;o<<=1) psum += __shfl_xor(psum, o);
      lsum[rr] = lsum[rr]*fac + psum;
      #pragma unroll
      for (int fn=0; fn<4; fn++) oacc[fn][rr] *= fac;
      // write P to LDS (bf16, swizzled); Ps rows are wave-private
      int row = w*16 + lg*4 + rr;
      int swz = (row & 7) << 4;
      float pv[4] = {p0,p1,p2,p3};
      #pragma unroll
      for (int fn=0; fn<4; fn++){
        int col = fn*16 + lr;
        int addr = row*128 + ((((col>>3)<<4) ^ swz)) + ((col&7)<<1);
        *(u16*)((char*)Ps + addr) = f2b(pv[fn]);
      }
    }
    __builtin_amdgcn_sched_barrier(0);   // pin P-writes before PV reads

    // ---- O += P V (no block barrier: each wave reads only its own Ps rows) ----
    #pragma unroll
    for (int ks=0; ks<2; ks++){
      const int c = ks*4 + lg;
      int rq = w*16 + lr;
      bfrag a = *(const bfrag*)((const char*)Ps + rq*128 + ((c ^ (rq&7))<<4));
      #pragma unroll
      for (int fn=0; fn<4; fn++){
        int n = fn*16 + lr;
        bfrag bb = *(const bfrag*)((const char*)Vt + n*128 + ((c ^ (n&7))<<4));
        oacc[fn] = __builtin_amdgcn_mfma_f32_16x16x32_bf16(a, bb, oacc[fn], 0, 0, 0);
      }
    }
    __syncthreads();   // safe to restage Ks/Vt/Ps
  }

  // ---- epilogue: O / l ----
  float inv[4];
  #pragma unroll
  for (int rr=0; rr<4; rr++) inv[rr] = 1.f / lsum[rr];
  #pragma unroll
  for (int fn=0; fn<4; fn++){
    int col = h*64 + fn*16 + lr;
    #pragma unroll
    for (int rr=0; rr<4; rr++){
      int qrow = s0 + w*16 + lg*4 + rr;
      Og[((size_t)(b*SS + qrow))*DD + col] = f2b(oacc[fn][rr] * inv[rr]);
    }
  }
}

// ---------------------------------------------------------------------------
// LayerNorm, 6-slot batched: grid 12288 (6 tensors x 2048 rows), D=1024.
// ---------------------------------------------------------------------------
struct LnArgs {
  const float* X[6]; const float* g[6]; const float* b[6]; u16* O[6];
};

__device__ __forceinline__ float block_reduce_sum(float v){
  #pragma unroll
  for (int o=32;o;o>>=1) v += __shfl_xor(v,o);
  __shared__ float sm[4];
  if ((threadIdx.x&63)==0) sm[threadIdx.x>>6] = v;
  __syncthreads();
  float r = sm[0]+sm[1]+sm[2]+sm[3];
  __syncthreads();
  return r;
}

__global__ __launch_bounds__(256)
void ln6_kernel(LnArgs args)
{
  const int bi = blockIdx.x >> 11;
  const int row = blockIdx.x & 2047;
  const float* x = args.X[bi] + (size_t)row*DD;
  const int t = threadIdx.x;
  float4 v = ((const float4*)x)[t];
  float mean = block_reduce_sum(v.x+v.y+v.z+v.w) * (1.f/DD);
  float d0=v.x-mean, d1=v.y-mean, d2=v.z-mean, d3=v.w-mean;
  float var = block_reduce_sum(d0*d0+d1*d1+d2*d2+d3*d3) * (1.f/DD);
  float rs = rsqrtf(var + 1e-5f);
  float4 gg = ((const float4*)args.g[bi])[t];
  float4 bb = ((const float4*)args.b[bi])[t];
  ushort4 o;
  o.x = f2b(d0*rs*gg.x + bb.x);
  o.y = f2b(d1*rs*gg.y + bb.y);
  o.z = f2b(d2*rs*gg.z + bb.z);
  o.w = f2b(d3*rs*gg.w + bb.w);
  ((ushort4*)(args.O[bi] + (size_t)row*DD))[t] = o;
}

__global__ __launch_bounds__(256)
void cvt3_kernel(const float* __restrict__ i0, const float* __restrict__ i1,
                 const float* __restrict__ i2, u16* __restrict__ o0,
                 u16* __restrict__ o1, u16* __restrict__ o2)
{
  const int sel = blockIdx.x >> 10;
  const float* in = sel==0 ? i0 : sel==1 ? i1 : i2;
  u16* out = sel==0 ? o0 : sel==1 ? o1 : o2;
  size_t i = (((size_t)(blockIdx.x & 1023))*256 + threadIdx.x)*8;
  float4 a = *(const float4*)(in+i);
  float4 b = *(const float4*)(in+i+4);
  ushort4 q0, q1;
  q0.x=f2b(a.x); q0.y=f2b(a.y); q0.z=f2b(a.z); q0.w=f2b(a.w);
  q1.x=f2b(b.x); q1.y=f2b(b.y); q1.z=f2b(b.z); q1.w=f2b(b.w);
  *(ushort4*)(out+i) = q0;
  *(ushort4*)(out+i+4) = q1;
}

// ---------------------------------------------------------------------------
extern "C" void kernel_launch(void* const* d_in, const int* in_sizes, int n_in,
                              void* d_out, int out_size, void* d_ws, size_t ws_size,
                              hipStream_t stream)
{
  (void)in_sizes; (void)n_in; (void)out_size; (void)ws_size;
  const float* text   = (const float*)d_in[0];
  const float* audio  = (const float*)d_in[1];
  const float* visual = (const float*)d_in[2];
  const float* WQ  = (const float*)d_in[3];
  const float* bQ  = (const float*)d_in[4];
  const float* WK  = (const float*)d_in[5];
  const float* bK  = (const float*)d_in[6];
  const float* WV1 = (const float*)d_in[7];
  const float* bV1 = (const float*)d_in[8];
  const float* WV2 = (const float*)d_in[9];
  const float* bV2 = (const float*)d_in[10];
  const float* WO1 = (const float*)d_in[11];
  const float* bO1 = (const float*)d_in[12];
  const float* WO2 = (const float*)d_in[13];
  const float* bO2 = (const float*)d_in[14];
  const float* F1W1 = (const float*)d_in[15];
  const float* F1b1 = (const float*)d_in[16];
  const float* F1W2 = (const float*)d_in[17];
  const float* F1b2 = (const float*)d_in[18];
  const float* F2W1 = (const float*)d_in[19];
  const float* F2b1 = (const float*)d_in[20];
  const float* F2W2 = (const float*)d_in[21];
  const float* F2b2 = (const float*)d_in[22];
  const float* LN1g = (const float*)d_in[23];
  const float* LN1b = (const float*)d_in[24];
  const float* LN2g = (const float*)d_in[25];
  const float* LN2b = (const float*)d_in[26];
  float* outp = (float*)d_out;

  // ws layout: round-15 proven 260 MB (212 + 48 JIT weight buffer).
  char* ws = (char*)d_ws;
  size_t off = 0;
  auto alloc = [&](size_t bytes)->char*{
    char* p = ws + off; off += (bytes + 255) & ~(size_t)255; return p;
  };
  const size_t NTOK = (size_t)BB*SS;          // 2048 rows
  const size_t AB = NTOK*DD*2;                // bf16 activation bytes (4MB)
  const size_t E  = NTOK*DD;                  // activation elements (2M)

  u16* inb[3];
  for (int i=0;i<3;i++) inb[i] = (u16*)alloc(AB);
  u16 *Qb[3], *Kb[3], *V1b[3], *V2b[3], *nV1b[3], *nV2b[3];
  for (int i=0;i<3;i++){
    Qb[i]=(u16*)alloc(AB); Kb[i]=(u16*)alloc(AB);
    V1b[i]=(u16*)alloc(AB); V2b[i]=(u16*)alloc(AB);
  }
  for (int i=0;i<3;i++){ nV1b[i]=(u16*)alloc(AB); nV2b[i]=(u16*)alloc(AB); }
  float* Lgp = (float*)alloc((size_t)BB*HH*SS*SS*4);   // 64MB (h-alias region)
  u16* P1p   = (u16*)alloc((size_t)BB*HH*SS*SS*2);     // 32MB (h-alias region)
  u16* P2Tp  = (u16*)alloc((size_t)BB*HH*SS*SS*2);     // 32MB (mid-alias region)
  u16* Wtb   = (u16*)alloc((size_t)6*DD*HID*2);        // 48MB JIT weight buffer

  // aliases (dead-phase reuse). h buffers are 4E elements each.
  u16 *x1b[3], *x2b[3], *h1b[3], *h2b[3], *mid1b[3], *mid2b[3];
  for (int i=0;i<3;i++){ x1b[i]=Qb[i]; x2b[i]=Kb[i]; }
  u16* Lgu = (u16*)Lgp;
  h1b[0]=Lgu;        h2b[0]=Lgu+ 4*E;   // Lg = 16E: four 4E h-buffers
  h1b[1]=Lgu+8*E;    h2b[1]=Lgu+12*E;
  h1b[2]=P1p;        h2b[2]=P1p+ 4*E;   // P1 = 16E: two 4E h-buffers
  for (int i=0;i<3;i++){ mid1b[i]=P2Tp+(size_t)(2*i)*E; mid2b[i]=P2Tp+(size_t)(2*i+1)*E; }

  cvt3_kernel<<<3072,256,0,stream>>>(text, audio, visual, inb[0], inb[1], inb[2]);

  const size_t OSZ = E;
  const size_t DD2 = (size_t)DD*DD;
  const size_t DH = (size_t)DD*HID;
  struct Br { const float* f1; const u16* b1; const float* f2; const u16* b2; int s1, s2; };
  Br brs[3] = {{text,inb[0],audio,inb[1],0,1},{text,inb[0],visual,inb[2],2,3},{audio,inb[1],visual,inb[2],4,5}};

  for (int li=0; li<2; li++){
    const u16* m1b[3]; const u16* m2b[3];
    float* t1f[3]; float* t2f[3];
    for (int bi=0; bi<3; bi++){
      m1b[bi] = li==0 ? brs[bi].b1 : mid1b[bi];
      m2b[bi] = li==0 ? brs[bi].b2 : mid2b[bi];
      t1f[bi] = outp + (size_t)brs[bi].s1*OSZ;   // residual stream lives in d_out
      t2f[bi] = outp + (size_t)brs[bi].s2*OSZ;
    }

    // ---- merged wcvt: proj (slots 0-11) + o-proj (slots 12-17), grid 4608 ----
    {
      WcvtArgs wa{};
      for (int bi=0; bi<3; bi++){
        const int i = bi*2 + li;
        wa.W[bi*4+0]=WQ +i*DD2; wa.W[bi*4+1]=WK +i*DD2;
        wa.W[bi*4+2]=WV1+i*DD2; wa.W[bi*4+3]=WV2+i*DD2;
        for (int s=0;s<4;s++) wa.Wt[bi*4+s] = Wtb + (size_t)(bi*4+s)*DD2;
        wa.W[12+bi*2+0]=WO1+i*DD2; wa.W[12+bi*2+1]=WO2+i*DD2;
        wa.Wt[12+bi*2+0]=Wtb + (size_t)(12+bi*2+0)*DD2;
        wa.Wt[12+bi*2+1]=Wtb + (size_t)(12+bi*2+1)*DD2;
      }
      wcvt_kernel<<<4608,256,0,stream>>>(wa, DD, DD);
    }
    // ---- projections: 12-slot GEMM (TN=128, grid 1536) ----
    {
      GemmArgs ga{};
      for (int bi=0; bi<3; bi++){
        const int i = bi*2 + li;
        ga.A[bi*4+0]=m1b[bi]; ga.bias[bi*4+0]=bQ +(size_t)i*DD; ga.Cb[bi*4+0]=Qb[bi];
        ga.A[bi*4+1]=m2b[bi]; ga.bias[bi*4+1]=bK +(size_t)i*DD; ga.Cb[bi*4+1]=Kb[bi];
        ga.A[bi*4+2]=m1b[bi]; ga.bias[bi*4+2]=bV1+(size_t)i*DD; ga.Cb[bi*4+2]=V1b[bi];
        ga.A[bi*4+3]=m2b[bi]; ga.bias[bi*4+3]=bV2+(size_t)i*DD; ga.Cb[bi*4+3]=V2b[bi];
        for (int s=0;s<4;s++) ga.W[bi*4+s] = Wtb + (size_t)(bi*4+s)*DD2;
      }
      ga.N = DD; ga.K = DD;
      gemm_kernel<0,128><<<1536,256,0,stream>>>(ga);
    }
    // ---- flash attention: 6 slots (3 branches x 2 dirs), grid 3072 ----
    {
      FlashArgs fa{};
      for (int bi=0; bi<3; bi++){
        fa.Q[bi*2+0]=Qb[bi]; fa.K[bi*2+0]=Kb[bi]; fa.V[bi*2+0]=V2b[bi]; fa.O[bi*2+0]=nV2b[bi];
        fa.Q[bi*2+1]=Kb[bi]; fa.K[bi*2+1]=Qb[bi]; fa.V[bi*2+1]=V1b[bi]; fa.O[bi*2+1]=nV1b[bi];
      }
      flash_kernel<<<3072,256,0,stream>>>(fa);
    }
    // ---- output projections: 6-slot GEMM (TN=128, grid 768; Wtb slots 12-17) ----
    {
      GemmArgs ga{};
      for (int bi=0; bi<3; bi++){
        const int i = bi*2 + li;
        ga.A[bi*2+0]=nV1b[bi]; ga.bias[bi*2+0]=bO1+(size_t)i*DD;
        ga.resid[bi*2+0] = li==0 ? brs[bi].f1 : t1f[bi]; ga.Cf[bi*2+0]=t1f[bi];
        ga.A[bi*2+1]=nV2b[bi]; ga.bias[bi*2+1]=bO2+(size_t)i*DD;
        ga.resid[bi*2+1] = li==0 ? brs[bi].f2 : t2f[bi]; ga.Cf[bi*2+1]=t2f[bi];
        ga.W[bi*2+0]=Wtb + (size_t)(12+bi*2+0)*DD2;
        ga.W[bi*2+1]=Wtb + (size_t)(12+bi*2+1)*DD2;
      }
      ga.N = DD; ga.K = DD;
      gemm_kernel<2,128><<<768,256,0,stream>>>(ga);
    }
    // ---- LN: single 6-slot dispatch, grid 12288 ----
    {
      LnArgs la{};
      for (int bi=0; bi<3; bi++){
        const int i = bi*2 + li;
        la.X[bi*2+0]=t1f[bi]; la.g[bi*2+0]=LN1g+(size_t)i*DD; la.b[bi*2+0]=LN1b+(size_t)i*DD; la.O[bi*2+0]=x1b[bi];
        la.X[bi*2+1]=t2f[bi]; la.g[bi*2+1]=LN2g+(size_t)i*DD; la.b[bi*2+1]=LN2b+(size_t)i*DD; la.O[bi*2+1]=x2b[bi];
      }
      ln6_kernel<<<12288,256,0,stream>>>(la);
    }
    // ---- FFN up: JIT-convert, then 6-slot GEMM (N=4096, TN=128, grid 3072) ----
    {
      WcvtArgs wa{};
      for (int bi=0; bi<3; bi++){
        const int i = bi*2 + li;
        wa.W[bi*2+0]=F1W1+(size_t)i*DH; wa.W[bi*2+1]=F2W1+(size_t)i*DH;
        wa.Wt[bi*2+0]=Wtb + (size_t)(bi*2+0)*DH;
        wa.Wt[bi*2+1]=Wtb + (size_t)(bi*2+1)*DH;
      }
      wcvt_kernel<<<6144,256,0,stream>>>(wa, DD, HID);
      GemmArgs ga{};
      for (int bi=0; bi<3; bi++){
        const int i = bi*2 + li;
        ga.A[bi*2+0]=x1b[bi]; ga.bias[bi*2+0]=F1b1+(size_t)i*HID; ga.Cb[bi*2+0]=h1b[bi];
        ga.A[bi*2+1]=x2b[bi]; ga.bias[bi*2+1]=F2b1+(size_t)i*HID; ga.Cb[bi*2+1]=h2b[bi];
        ga.W[bi*2+0]=Wtb + (size_t)(bi*2+0)*DH;
        ga.W[bi*2+1]=Wtb + (size_t)(bi*2+1)*DH;
      }
      ga.N = HID; ga.K = DD;
      gemm_kernel<1,128><<<3072,256,0,stream>>>(ga);
    }
    // ---- FFN down: JIT-convert, then 6-slot GEMM (K=4096, TN=128, grid 768) ----
    {
      WcvtArgs wa{};
      for (int bi=0; bi<3; bi++){
        const int i = bi*2 + li;
        wa.W[bi*2+0]=F1W2+(size_t)i*DH; wa.W[bi*2+1]=F2W2+(size_t)i*DH;
        wa.Wt[bi*2+0]=Wtb + (size_t)(bi*2+0)*DH;
        wa.Wt[bi*2+1]=Wtb + (size_t)(bi*2+1)*DH;
      }
      wcvt_kernel<<<6144,256,0,stream>>>(wa, HID, DD);
      GemmArgs ga{};
      for (int bi=0; bi<3; bi++){
        const int i = bi*2 + li;
        ga.A[bi*2+0]=h1b[bi]; ga.bias[bi*2+0]=F1b2+(size_t)i*DD;
        ga.resid[bi*2+0]=t1f[bi]; ga.Cf[bi*2+0]=t1f[bi]; ga.Cb[bi*2+0]=mid1b[bi];
        ga.A[bi*2+1]=h2b[bi]; ga.bias[bi*2+1]=F2b2+(size_t)i*DD;
        ga.resid[bi*2+1]=t2f[bi]; ga.Cf[bi*2+1]=t2f[bi]; ga.Cb[bi*2+1]=mid2b[bi];
        ga.W[bi*2+0]=Wtb + (size_t)(bi*2+0)*DH;
        ga.W[bi*2+1]=Wtb + (size_t)(bi*2+1)*DH;
      }
      ga.N = DD; ga.K = HID;
      if (li == 0) gemm_kernel<3,128><<<768,256,0,stream>>>(ga);
      else         gemm_kernel<2,128><<<768,256,0,stream>>>(ga);
    }
  }
}